// Round 3
// baseline (210.572 us; speedup 1.0000x reference)
//
#include <hip/hip_runtime.h>
#include <math.h>

#define T_STEPS 22
#define F_IN    12
#define HID     32

typedef __attribute__((ext_vector_type(8))) short  bf16x8;
typedef __attribute__((ext_vector_type(16))) float f32x16;

union FragU { unsigned int u[4]; bf16x8 v; };

#define LOG2E   1.442695041f
#define TWOLOG2E 2.885390082f

static __device__ __forceinline__ unsigned short f2bf(float x) {
    unsigned int u = __builtin_bit_cast(unsigned int, x);
    return (unsigned short)((u + 0x7fffu + ((u >> 16) & 1u)) >> 16);
}

static __device__ __forceinline__ unsigned cvt_pk_bf16(float lo, float hi) {
    unsigned r;
    asm("v_cvt_pk_bf16_f32 %0, %1, %2" : "=v"(r) : "v"(lo), "v"(hi));
    return r;
}

// ws layout (floats):
//   [0,1024)    wx_frag: [4 m][64 lane] x 8 bf16, rows prescaled; k=12 = fused bias
//   [1024,3072) wh_frag: [4 m][2 kt][64 lane] x 8 bf16, rows prescaled
//   [3072,3104) whead:   [2 hi][16 q] f32 permuted to C-layout rows
__global__ void prep_kernel(const float* __restrict__ Wih, const float* __restrict__ Whh,
                            const float* __restrict__ bih, const float* __restrict__ bhh,
                            const float* __restrict__ Whead, float* __restrict__ ws) {
    const int tid = threadIdx.x;  // 256
    unsigned short* wx = (unsigned short*)ws;
    unsigned short* wh = (unsigned short*)(ws + 1024);
    float* whd = ws + 3072;

    {   // wx: entry = m*64 + lane (== tid)
        int m = tid >> 6, lane = tid & 63;
        int g = 32 * m + (lane & 31);
        float scale = (m == 2) ? TWOLOG2E : -LOG2E;   // g-gate: +2log2e; i,f,o: -log2e
        int kbase = 8 * (lane >> 5);
        for (int j = 0; j < 8; ++j) {
            int k = kbase + j;
            float v = 0.0f;
            if (k < F_IN)       v = Wih[g * F_IN + k];
            else if (k == F_IN) v = bih[g] + bhh[g];
            wx[tid * 8 + j] = f2bf(scale * v);
        }
    }
    for (int e = tid; e < 4 * 2 * 64; e += 256) {
        int m = e >> 7, kt = (e >> 6) & 1, lane = e & 63;
        int g = 32 * m + (lane & 31);
        float scale = (m == 2) ? TWOLOG2E : -LOG2E;
        int kbase = 16 * kt + 8 * (lane >> 5);
        for (int j = 0; j < 8; ++j)
            wh[e * 8 + j] = f2bf(scale * Whh[g * HID + kbase + j]);
    }
    if (tid < 32) {
        int hi = tid >> 4, q = tid & 15;
        int j = (q & 3) + 8 * (q >> 2) + 4 * hi;
        whd[tid] = Whead[j];
    }
}

__global__ void __launch_bounds__(256, 4)
lstm_kernel(const float* __restrict__ x, const float* __restrict__ ws,
            const float* __restrict__ bheadp, float* __restrict__ out, int B) {
    const int lane = threadIdx.x & 63;
    const int wave = threadIdx.x >> 6;
    const int col  = lane & 31;
    const int hi   = lane >> 5;
    int b = blockIdx.x * 128 + wave * 32 + col;
    const bool valid = (b < B);
    if (b >= B) b = B - 1;

    const bf16x8* wxp = (const bf16x8*)ws;
    const bf16x8* whp = (const bf16x8*)(ws + 1024);
    bf16x8 wxf[4], whf[4][2];
#pragma unroll
    for (int m = 0; m < 4; ++m) wxf[m] = wxp[m * 64 + lane];
#pragma unroll
    for (int m = 0; m < 4; ++m)
#pragma unroll
        for (int kt = 0; kt < 2; ++kt) whf[m][kt] = whp[(m * 2 + kt) * 64 + lane];

    // lo lanes read x[0..3],x[4..7]; hi lanes read x[8..11] (second load aliases, unused)
    const float* xb1 = x + (size_t)b * (T_STEPS * F_IN) + (hi ? 8 : 0);
    const float* xb2 = x + (size_t)b * (T_STEPS * F_IN) + (hi ? 8 : 4);

    float c[16], hv[16];
#pragma unroll
    for (int q = 0; q < 16; ++q) { c[q] = 0.0f; hv[q] = 0.0f; }
    bf16x8 hf0, hf1;
#pragma unroll
    for (int j = 0; j < 8; ++j) { hf0[j] = 0; hf1[j] = 0; }

    f32x16 zc;   // hoisted zero C-in (avoids re-zeroing 64 regs per step)
#pragma unroll
    for (int q = 0; q < 16; ++q) zc[q] = 0.0f;

    float4 va = *(const float4*)(xb1);
    float4 vb = *(const float4*)(xb2);

#pragma unroll
    for (int t = 0; t < T_STEPS; ++t) {
        // prefetch next step's x (consumed ~1 full step later)
        const int tn = (t + 1 < T_STEPS) ? t + 1 : t;
        float4 na = *(const float4*)(xb1 + tn * F_IN);
        float4 nb = *(const float4*)(xb2 + tn * F_IN);

        FragU xf;
        xf.u[0] = cvt_pk_bf16(va.x, va.y);
        xf.u[1] = cvt_pk_bf16(va.z, va.w);
        unsigned w2 = cvt_pk_bf16(vb.x, vb.y);
        unsigned w3 = cvt_pk_bf16(vb.z, vb.w);
        xf.u[2] = hi ? 0x00003f80u : w2;   // k=12 -> 1.0 (bias feature), k=13 weightless
        xf.u[3] = hi ? 0u : w3;

        f32x16 a0, a1, a2, a3;
        a0 = __builtin_amdgcn_mfma_f32_32x32x16_bf16(wxf[0], xf.v, zc, 0, 0, 0);
        a1 = __builtin_amdgcn_mfma_f32_32x32x16_bf16(wxf[1], xf.v, zc, 0, 0, 0);
        a2 = __builtin_amdgcn_mfma_f32_32x32x16_bf16(wxf[2], xf.v, zc, 0, 0, 0);
        a3 = __builtin_amdgcn_mfma_f32_32x32x16_bf16(wxf[3], xf.v, zc, 0, 0, 0);
        if (t > 0) {
            a0 = __builtin_amdgcn_mfma_f32_32x32x16_bf16(whf[0][0], hf0, a0, 0, 0, 0);
            a1 = __builtin_amdgcn_mfma_f32_32x32x16_bf16(whf[1][0], hf0, a1, 0, 0, 0);
            a2 = __builtin_amdgcn_mfma_f32_32x32x16_bf16(whf[2][0], hf0, a2, 0, 0, 0);
            a3 = __builtin_amdgcn_mfma_f32_32x32x16_bf16(whf[3][0], hf0, a3, 0, 0, 0);
            a0 = __builtin_amdgcn_mfma_f32_32x32x16_bf16(whf[0][1], hf1, a0, 0, 0, 0);
            a1 = __builtin_amdgcn_mfma_f32_32x32x16_bf16(whf[1][1], hf1, a1, 0, 0, 0);
            a2 = __builtin_amdgcn_mfma_f32_32x32x16_bf16(whf[2][1], hf1, a2, 0, 0, 0);
            a3 = __builtin_amdgcn_mfma_f32_32x32x16_bf16(whf[3][1], hf1, a3, 0, 0, 0);
        }

        // cell in prescaled space: sig(a)=rcp(1+exp2(a')); c is 2log2e-scaled
#pragma unroll
        for (int q = 0; q < 16; ++q) {
            float ri = __builtin_amdgcn_rcpf(1.0f + __builtin_amdgcn_exp2f(a0[q]));
            float rg = __builtin_amdgcn_rcpf(1.0f + __builtin_amdgcn_exp2f(a2[q]));
            float ro = __builtin_amdgcn_rcpf(1.0f + __builtin_amdgcn_exp2f(a3[q]));
            float gs = fmaf(-2.0f * TWOLOG2E, rg, TWOLOG2E);   // 2log2e * tanh(g)
            if (t > 0) {
                float rf = __builtin_amdgcn_rcpf(1.0f + __builtin_amdgcn_exp2f(a1[q]));
                c[q] = fmaf(rf, c[q], ri * gs);
            } else {
                c[q] = ri * gs;
            }
            float tc = fmaf(-2.0f, __builtin_amdgcn_rcpf(1.0f + __builtin_amdgcn_exp2f(c[q])), 1.0f);
            hv[q] = ro * tc;
        }

        // repack h (C-layout) -> next B-fragments: cvt_pk pairs + lane<->lane+32 swaps
        unsigned P0 = cvt_pk_bf16(hv[0],  hv[1]);
        unsigned P1 = cvt_pk_bf16(hv[2],  hv[3]);
        unsigned P2 = cvt_pk_bf16(hv[4],  hv[5]);
        unsigned P3 = cvt_pk_bf16(hv[6],  hv[7]);
        unsigned P4 = cvt_pk_bf16(hv[8],  hv[9]);
        unsigned P5 = cvt_pk_bf16(hv[10], hv[11]);
        unsigned P6 = cvt_pk_bf16(hv[12], hv[13]);
        unsigned P7 = cvt_pk_bf16(hv[14], hv[15]);
        asm("v_permlane32_swap_b32 %0, %1" : "+v"(P0), "+v"(P2));
        asm("v_permlane32_swap_b32 %0, %1" : "+v"(P1), "+v"(P3));
        asm("v_permlane32_swap_b32 %0, %1" : "+v"(P4), "+v"(P6));
        asm("v_permlane32_swap_b32 %0, %1" : "+v"(P5), "+v"(P7));
        FragU h0; h0.u[0] = P0; h0.u[1] = P1; h0.u[2] = P2; h0.u[3] = P3;
        FragU h1; h1.u[0] = P4; h1.u[1] = P5; h1.u[2] = P6; h1.u[3] = P7;
        hf0 = h0.v;
        hf1 = h1.v;

        va = na; vb = nb;
    }

    // head: y = h . Whead + bhead ; softplus
    const float* whd = ws + 3072 + hi * 16;
    float y = 0.0f;
#pragma unroll
    for (int q = 0; q < 16; ++q) y = fmaf(hv[q], whd[q], y);
    y += __shfl_xor(y, 32, 64);
    y += bheadp[0];
    float sp = fmaxf(y, 0.0f) + log1pf(expf(-fabsf(y)));
    if (valid && hi == 0) out[b] = sp;
}

extern "C" void kernel_launch(void* const* d_in, const int* in_sizes, int n_in,
                              void* d_out, int out_size, void* d_ws, size_t ws_size,
                              hipStream_t stream) {
    const float* x     = (const float*)d_in[0];
    const float* Wih   = (const float*)d_in[1];
    const float* Whh   = (const float*)d_in[2];
    const float* bih   = (const float*)d_in[3];
    const float* bhh   = (const float*)d_in[4];
    const float* Whead = (const float*)d_in[5];
    const float* bhead = (const float*)d_in[6];
    float* out = (float*)d_out;
    float* ws  = (float*)d_ws;

    const int B = in_sizes[0] / (T_STEPS * F_IN);
    const int blocks = (B + 127) / 128;

    hipLaunchKernelGGL(prep_kernel, dim3(1), dim3(256), 0, stream,
                       Wih, Whh, bih, bhh, Whead, ws);
    hipLaunchKernelGGL(lstm_kernel, dim3(blocks), dim3(256), 0, stream,
                       x, ws, bhead, out, B);
}

// Round 4
// 177.467 us; speedup vs baseline: 1.1865x; 1.1865x over previous
//
#include <hip/hip_runtime.h>
#include <math.h>

#define T_STEPS 22
#define F_IN    12
#define HID     32

typedef __attribute__((ext_vector_type(8))) short  bf16x8;
typedef __attribute__((ext_vector_type(16))) float f32x16;

union FragU { unsigned int u[4]; bf16x8 v; };

#define LOG2E    1.442695041f
#define TWOLOG2E 2.885390082f

static __device__ __forceinline__ unsigned short f2bf(float x) {
    unsigned int u = __builtin_bit_cast(unsigned int, x);
    return (unsigned short)((u + 0x7fffu + ((u >> 16) & 1u)) >> 16);
}

static __device__ __forceinline__ unsigned cvt_pk_bf16(float lo, float hi) {
    unsigned r;
    asm("v_cvt_pk_bf16_f32 %0, %1, %2" : "=v"(r) : "v"(lo), "v"(hi));
    return r;
}

// ws layout (floats):
//   [0,1024)    wx_frag: [4 m][64 lane] x 8 bf16, rows prescaled; k=12 = fused bias
//   [1024,3072) wh_frag: [4 m][2 kt][64 lane] x 8 bf16, rows prescaled
//   [3072,3104) whead:   [2 hi][16 q] f32 permuted to C-layout rows
__global__ void prep_kernel(const float* __restrict__ Wih, const float* __restrict__ Whh,
                            const float* __restrict__ bih, const float* __restrict__ bhh,
                            const float* __restrict__ Whead, float* __restrict__ ws) {
    const int tid = threadIdx.x;  // 256
    unsigned short* wx = (unsigned short*)ws;
    unsigned short* wh = (unsigned short*)(ws + 1024);
    float* whd = ws + 3072;

    {   // wx: entry = m*64 + lane (== tid)
        int m = tid >> 6, lane = tid & 63;
        int g = 32 * m + (lane & 31);
        float scale = (m == 2) ? TWOLOG2E : -LOG2E;   // g-gate: +2log2e; i,f,o: -log2e
        int kbase = 8 * (lane >> 5);
        for (int j = 0; j < 8; ++j) {
            int k = kbase + j;
            float v = 0.0f;
            if (k < F_IN)       v = Wih[g * F_IN + k];
            else if (k == F_IN) v = bih[g] + bhh[g];
            wx[tid * 8 + j] = f2bf(scale * v);
        }
    }
    for (int e = tid; e < 4 * 2 * 64; e += 256) {
        int m = e >> 7, kt = (e >> 6) & 1, lane = e & 63;
        int g = 32 * m + (lane & 31);
        float scale = (m == 2) ? TWOLOG2E : -LOG2E;
        int kbase = 16 * kt + 8 * (lane >> 5);
        for (int j = 0; j < 8; ++j)
            wh[e * 8 + j] = f2bf(scale * Whh[g * HID + kbase + j]);
    }
    if (tid < 32) {
        int hi = tid >> 4, q = tid & 15;
        int j = (q & 3) + 8 * (q >> 2) + 4 * hi;
        whd[tid] = Whead[j];
    }
}

// 1-wave workgroups: co-residency limited only by VGPRs (~6 waves/SIMD),
// not by 4-waves-per-block granularity -> better trans-pipe saturation.
__global__ void __launch_bounds__(64, 4)
lstm_kernel(const float* __restrict__ x, const float* __restrict__ ws,
            const float* __restrict__ bheadp, float* __restrict__ out, int B) {
    const int lane = threadIdx.x;   // 0..63
    const int col  = lane & 31;
    const int hi   = lane >> 5;
    int b = blockIdx.x * 32 + col;
    const bool valid = (b < B);
    if (b >= B) b = B - 1;

    const bf16x8* wxp = (const bf16x8*)ws;
    const bf16x8* whp = (const bf16x8*)(ws + 1024);
    bf16x8 wxf[4], whf[4][2];
#pragma unroll
    for (int m = 0; m < 4; ++m) wxf[m] = wxp[m * 64 + lane];
#pragma unroll
    for (int m = 0; m < 4; ++m)
#pragma unroll
        for (int kt = 0; kt < 2; ++kt) whf[m][kt] = whp[(m * 2 + kt) * 64 + lane];

    // lo lanes read x[0..3],x[4..7]; hi lanes read x[8..11] (2nd load unused there)
    const float* xb1 = x + (size_t)b * (T_STEPS * F_IN) + (hi ? 8 : 0);
    const float* xb2 = x + (size_t)b * (T_STEPS * F_IN) + (hi ? 8 : 4);

    float c[16], hv[16];
#pragma unroll
    for (int q = 0; q < 16; ++q) { c[q] = 0.0f; hv[q] = 0.0f; }
    bf16x8 hf0, hf1;
#pragma unroll
    for (int j = 0; j < 8; ++j) { hf0[j] = 0; hf1[j] = 0; }

    f32x16 zc;   // hoisted zero C-in
#pragma unroll
    for (int q = 0; q < 16; ++q) zc[q] = 0.0f;

    float4 va = *(const float4*)(xb1);
    float4 vb = *(const float4*)(xb2);

    for (int t = 0; t < T_STEPS; ++t) {
        // prefetch next step's x (consumed a full step later; clamp at tail)
        const int tn = (t + 1 < T_STEPS) ? t + 1 : t;
        float4 na = *(const float4*)(xb1 + tn * F_IN);
        float4 nb = *(const float4*)(xb2 + tn * F_IN);

        FragU xf;
        xf.u[0] = cvt_pk_bf16(va.x, va.y);
        xf.u[1] = cvt_pk_bf16(va.z, va.w);
        unsigned w2 = cvt_pk_bf16(vb.x, vb.y);
        unsigned w3 = cvt_pk_bf16(vb.z, vb.w);
        xf.u[2] = hi ? 0x00003f80u : w2;   // k=12 -> 1.0 (fused bias feature)
        xf.u[3] = hi ? 0u : w3;

        f32x16 a0, a1, a2, a3;
        a0 = __builtin_amdgcn_mfma_f32_32x32x16_bf16(wxf[0], xf.v, zc, 0, 0, 0);
        a1 = __builtin_amdgcn_mfma_f32_32x32x16_bf16(wxf[1], xf.v, zc, 0, 0, 0);
        a2 = __builtin_amdgcn_mfma_f32_32x32x16_bf16(wxf[2], xf.v, zc, 0, 0, 0);
        a3 = __builtin_amdgcn_mfma_f32_32x32x16_bf16(wxf[3], xf.v, zc, 0, 0, 0);
        a0 = __builtin_amdgcn_mfma_f32_32x32x16_bf16(whf[0][0], hf0, a0, 0, 0, 0);
        a1 = __builtin_amdgcn_mfma_f32_32x32x16_bf16(whf[1][0], hf0, a1, 0, 0, 0);
        a2 = __builtin_amdgcn_mfma_f32_32x32x16_bf16(whf[2][0], hf0, a2, 0, 0, 0);
        a3 = __builtin_amdgcn_mfma_f32_32x32x16_bf16(whf[3][0], hf0, a3, 0, 0, 0);
        a0 = __builtin_amdgcn_mfma_f32_32x32x16_bf16(whf[0][1], hf1, a0, 0, 0, 0);
        a1 = __builtin_amdgcn_mfma_f32_32x32x16_bf16(whf[1][1], hf1, a1, 0, 0, 0);
        a2 = __builtin_amdgcn_mfma_f32_32x32x16_bf16(whf[2][1], hf1, a2, 0, 0, 0);
        a3 = __builtin_amdgcn_mfma_f32_32x32x16_bf16(whf[3][1], hf1, a3, 0, 0, 0);

        // cell in prescaled space: sig(a)=rcp(1+exp2(a')); c is 2log2e-scaled
#pragma unroll
        for (int q = 0; q < 16; ++q) {
            float ri = __builtin_amdgcn_rcpf(1.0f + __builtin_amdgcn_exp2f(a0[q]));
            float rf = __builtin_amdgcn_rcpf(1.0f + __builtin_amdgcn_exp2f(a1[q]));
            float rg = __builtin_amdgcn_rcpf(1.0f + __builtin_amdgcn_exp2f(a2[q]));
            float ro = __builtin_amdgcn_rcpf(1.0f + __builtin_amdgcn_exp2f(a3[q]));
            float gs = fmaf(-2.0f * TWOLOG2E, rg, TWOLOG2E);   // 2log2e * tanh(g)
            c[q] = fmaf(rf, c[q], ri * gs);
            float tc = fmaf(-2.0f, __builtin_amdgcn_rcpf(1.0f + __builtin_amdgcn_exp2f(c[q])), 1.0f);
            hv[q] = ro * tc;
        }

        // repack h (C-layout) -> next B-fragments
        unsigned P0 = cvt_pk_bf16(hv[0],  hv[1]);
        unsigned P1 = cvt_pk_bf16(hv[2],  hv[3]);
        unsigned P2 = cvt_pk_bf16(hv[4],  hv[5]);
        unsigned P3 = cvt_pk_bf16(hv[6],  hv[7]);
        unsigned P4 = cvt_pk_bf16(hv[8],  hv[9]);
        unsigned P5 = cvt_pk_bf16(hv[10], hv[11]);
        unsigned P6 = cvt_pk_bf16(hv[12], hv[13]);
        unsigned P7 = cvt_pk_bf16(hv[14], hv[15]);
        asm("v_permlane32_swap_b32 %0, %1" : "+v"(P0), "+v"(P2));
        asm("v_permlane32_swap_b32 %0, %1" : "+v"(P1), "+v"(P3));
        asm("v_permlane32_swap_b32 %0, %1" : "+v"(P4), "+v"(P6));
        asm("v_permlane32_swap_b32 %0, %1" : "+v"(P5), "+v"(P7));
        FragU h0; h0.u[0] = P0; h0.u[1] = P1; h0.u[2] = P2; h0.u[3] = P3;
        FragU h1; h1.u[0] = P4; h1.u[1] = P5; h1.u[2] = P6; h1.u[3] = P7;
        hf0 = h0.v;
        hf1 = h1.v;

        va = na; vb = nb;
    }

    // head: y = h . Whead + bhead ; softplus
    const float* whd = ws + 3072 + hi * 16;
    float y = 0.0f;
#pragma unroll
    for (int q = 0; q < 16; ++q) y = fmaf(hv[q], whd[q], y);
    y += __shfl_xor(y, 32, 64);
    y += bheadp[0];
    float sp = fmaxf(y, 0.0f) + log1pf(expf(-fabsf(y)));
    if (valid && hi == 0) out[b] = sp;
}

extern "C" void kernel_launch(void* const* d_in, const int* in_sizes, int n_in,
                              void* d_out, int out_size, void* d_ws, size_t ws_size,
                              hipStream_t stream) {
    const float* x     = (const float*)d_in[0];
    const float* Wih   = (const float*)d_in[1];
    const float* Whh   = (const float*)d_in[2];
    const float* bih   = (const float*)d_in[3];
    const float* bhh   = (const float*)d_in[4];
    const float* Whead = (const float*)d_in[5];
    const float* bhead = (const float*)d_in[6];
    float* out = (float*)d_out;
    float* ws  = (float*)d_ws;

    const int B = in_sizes[0] / (T_STEPS * F_IN);
    const int blocks = (B + 31) / 32;

    hipLaunchKernelGGL(prep_kernel, dim3(1), dim3(256), 0, stream,
                       Wih, Whh, bih, bhh, Whead, ws);
    hipLaunchKernelGGL(lstm_kernel, dim3(blocks), dim3(64), 0, stream,
                       x, ws, bhead, out, B);
}

// Round 5
// 96.323 us; speedup vs baseline: 2.1861x; 1.8424x over previous
//
#include <hip/hip_runtime.h>
#include <math.h>

#define T_STEPS 22
#define F_IN    12
#define HID     32

typedef __attribute__((ext_vector_type(8))) short  bf16x8;
typedef __attribute__((ext_vector_type(16))) float f32x16;

union FragU { unsigned int u[4]; bf16x8 v; };

#define LOG2E    1.442695041f
#define TWOLOG2E 2.885390082f

static __device__ __forceinline__ unsigned short f2bf(float x) {
    unsigned int u = __builtin_bit_cast(unsigned int, x);
    return (unsigned short)((u + 0x7fffu + ((u >> 16) & 1u)) >> 16);
}

static __device__ __forceinline__ unsigned cvt_pk_bf16(float lo, float hi) {
    unsigned r;
    asm("v_cvt_pk_bf16_f32 %0, %1, %2" : "=v"(r) : "v"(lo), "v"(hi));
    return r;
}

// ws layout (floats):
//   [0,1024)    wx_frag: [4 m][64 lane] x 8 bf16, rows prescaled; k=12 = fused bias
//   [1024,3072) wh_frag: [4 m][2 kt][64 lane] x 8 bf16, rows prescaled
//   [3072,3104) whead:   [2 hi][16 q] f32 permuted to C-layout rows
__global__ void prep_kernel(const float* __restrict__ Wih, const float* __restrict__ Whh,
                            const float* __restrict__ bih, const float* __restrict__ bhh,
                            const float* __restrict__ Whead, float* __restrict__ ws) {
    const int tid = threadIdx.x;  // 256
    unsigned short* wx = (unsigned short*)ws;
    unsigned short* wh = (unsigned short*)(ws + 1024);
    float* whd = ws + 3072;

    {   // wx: entry = m*64 + lane (== tid)
        int m = tid >> 6, lane = tid & 63;
        int g = 32 * m + (lane & 31);
        float scale = (m == 2) ? TWOLOG2E : -LOG2E;   // g-gate: +2log2e; i,f,o: -log2e
        int kbase = 8 * (lane >> 5);
        for (int j = 0; j < 8; ++j) {
            int k = kbase + j;
            float v = 0.0f;
            if (k < F_IN)       v = Wih[g * F_IN + k];
            else if (k == F_IN) v = bih[g] + bhh[g];
            wx[tid * 8 + j] = f2bf(scale * v);
        }
    }
    for (int e = tid; e < 4 * 2 * 64; e += 256) {
        int m = e >> 7, kt = (e >> 6) & 1, lane = e & 63;
        int g = 32 * m + (lane & 31);
        float scale = (m == 2) ? TWOLOG2E : -LOG2E;
        int kbase = 16 * kt + 8 * (lane >> 5);
        for (int j = 0; j < 8; ++j)
            wh[e * 8 + j] = f2bf(scale * Whh[g * HID + kbase + j]);
    }
    if (tid < 32) {
        int hi = tid >> 4, q = tid & 15;
        int j = (q & 3) + 8 * (q >> 2) + 4 * hi;
        whd[tid] = Whead[j];
    }
}

// Round-2-proven register structure: generous VGPR cap (no spills), loads in
// loop body (no double-buffer state), per-step accumulator init.
__global__ void __launch_bounds__(256, 2)
lstm_kernel(const float* __restrict__ x, const float* __restrict__ ws,
            const float* __restrict__ bheadp, float* __restrict__ out, int B) {
    const int lane = threadIdx.x & 63;
    const int wave = threadIdx.x >> 6;
    const int col  = lane & 31;
    const int hi   = lane >> 5;
    int b = blockIdx.x * 128 + wave * 32 + col;
    const bool valid = (b < B);
    if (b >= B) b = B - 1;

    const bf16x8* wxp = (const bf16x8*)ws;
    const bf16x8* whp = (const bf16x8*)(ws + 1024);
    bf16x8 wxf[4], whf[4][2];
#pragma unroll
    for (int m = 0; m < 4; ++m) wxf[m] = wxp[m * 64 + lane];
#pragma unroll
    for (int m = 0; m < 4; ++m)
#pragma unroll
        for (int kt = 0; kt < 2; ++kt) whf[m][kt] = whp[(m * 2 + kt) * 64 + lane];

    // lo lanes read x[0..3],x[4..7]; hi lanes read x[8..11] (2nd load unused there)
    const float* xb1 = x + (size_t)b * (T_STEPS * F_IN) + (hi ? 8 : 0);
    const float* xb2 = x + (size_t)b * (T_STEPS * F_IN) + (hi ? 8 : 4);

    float c[16], hv[16];
#pragma unroll
    for (int q = 0; q < 16; ++q) { c[q] = 0.0f; hv[q] = 0.0f; }
    bf16x8 hf0, hf1;
#pragma unroll
    for (int j = 0; j < 8; ++j) { hf0[j] = 0; hf1[j] = 0; }

    for (int t = 0; t < T_STEPS; ++t) {
        float4 va = *(const float4*)(xb1 + t * F_IN);
        float4 vb = *(const float4*)(xb2 + t * F_IN);

        FragU xf;
        xf.u[0] = cvt_pk_bf16(va.x, va.y);
        xf.u[1] = cvt_pk_bf16(va.z, va.w);
        unsigned w2 = cvt_pk_bf16(vb.x, vb.y);
        unsigned w3 = cvt_pk_bf16(vb.z, vb.w);
        xf.u[2] = hi ? 0x00003f80u : w2;   // k=12 -> 1.0 (fused bias feature)
        xf.u[3] = hi ? 0u : w3;

        f32x16 a0, a1, a2, a3;
#pragma unroll
        for (int q = 0; q < 16; ++q) { a0[q] = 0.f; a1[q] = 0.f; a2[q] = 0.f; a3[q] = 0.f; }

        a0 = __builtin_amdgcn_mfma_f32_32x32x16_bf16(wxf[0], xf.v, a0, 0, 0, 0);
        a1 = __builtin_amdgcn_mfma_f32_32x32x16_bf16(wxf[1], xf.v, a1, 0, 0, 0);
        a2 = __builtin_amdgcn_mfma_f32_32x32x16_bf16(wxf[2], xf.v, a2, 0, 0, 0);
        a3 = __builtin_amdgcn_mfma_f32_32x32x16_bf16(wxf[3], xf.v, a3, 0, 0, 0);
        a0 = __builtin_amdgcn_mfma_f32_32x32x16_bf16(whf[0][0], hf0, a0, 0, 0, 0);
        a1 = __builtin_amdgcn_mfma_f32_32x32x16_bf16(whf[1][0], hf0, a1, 0, 0, 0);
        a2 = __builtin_amdgcn_mfma_f32_32x32x16_bf16(whf[2][0], hf0, a2, 0, 0, 0);
        a3 = __builtin_amdgcn_mfma_f32_32x32x16_bf16(whf[3][0], hf0, a3, 0, 0, 0);
        a0 = __builtin_amdgcn_mfma_f32_32x32x16_bf16(whf[0][1], hf1, a0, 0, 0, 0);
        a1 = __builtin_amdgcn_mfma_f32_32x32x16_bf16(whf[1][1], hf1, a1, 0, 0, 0);
        a2 = __builtin_amdgcn_mfma_f32_32x32x16_bf16(whf[2][1], hf1, a2, 0, 0, 0);
        a3 = __builtin_amdgcn_mfma_f32_32x32x16_bf16(whf[3][1], hf1, a3, 0, 0, 0);

        // cell in prescaled space: sig(a)=rcp(1+exp2(a')); c is 2log2e-scaled
#pragma unroll
        for (int q = 0; q < 16; ++q) {
            float ri = __builtin_amdgcn_rcpf(1.0f + __builtin_amdgcn_exp2f(a0[q]));
            float rf = __builtin_amdgcn_rcpf(1.0f + __builtin_amdgcn_exp2f(a1[q]));
            float rg = __builtin_amdgcn_rcpf(1.0f + __builtin_amdgcn_exp2f(a2[q]));
            float ro = __builtin_amdgcn_rcpf(1.0f + __builtin_amdgcn_exp2f(a3[q]));
            float gs = fmaf(-2.0f * TWOLOG2E, rg, TWOLOG2E);   // 2log2e * tanh(g)
            c[q] = fmaf(rf, c[q], ri * gs);
            float tc = fmaf(-2.0f, __builtin_amdgcn_rcpf(1.0f + __builtin_amdgcn_exp2f(c[q])), 1.0f);
            hv[q] = ro * tc;
        }

        // repack h (C-layout) -> next B-fragments
        unsigned P0 = cvt_pk_bf16(hv[0],  hv[1]);
        unsigned P1 = cvt_pk_bf16(hv[2],  hv[3]);
        unsigned P2 = cvt_pk_bf16(hv[4],  hv[5]);
        unsigned P3 = cvt_pk_bf16(hv[6],  hv[7]);
        unsigned P4 = cvt_pk_bf16(hv[8],  hv[9]);
        unsigned P5 = cvt_pk_bf16(hv[10], hv[11]);
        unsigned P6 = cvt_pk_bf16(hv[12], hv[13]);
        unsigned P7 = cvt_pk_bf16(hv[14], hv[15]);
        asm("v_permlane32_swap_b32 %0, %1" : "+v"(P0), "+v"(P2));
        asm("v_permlane32_swap_b32 %0, %1" : "+v"(P1), "+v"(P3));
        asm("v_permlane32_swap_b32 %0, %1" : "+v"(P4), "+v"(P6));
        asm("v_permlane32_swap_b32 %0, %1" : "+v"(P5), "+v"(P7));
        FragU h0; h0.u[0] = P0; h0.u[1] = P1; h0.u[2] = P2; h0.u[3] = P3;
        FragU h1; h1.u[0] = P4; h1.u[1] = P5; h1.u[2] = P6; h1.u[3] = P7;
        hf0 = h0.v;
        hf1 = h1.v;
    }

    // head: y = h . Whead + bhead ; softplus
    const float* whd = ws + 3072 + hi * 16;
    float y = 0.0f;
#pragma unroll
    for (int q = 0; q < 16; ++q) y = fmaf(hv[q], whd[q], y);
    y += __shfl_xor(y, 32, 64);
    y += bheadp[0];
    float sp = fmaxf(y, 0.0f) + log1pf(expf(-fabsf(y)));
    if (valid && hi == 0) out[b] = sp;
}

extern "C" void kernel_launch(void* const* d_in, const int* in_sizes, int n_in,
                              void* d_out, int out_size, void* d_ws, size_t ws_size,
                              hipStream_t stream) {
    const float* x     = (const float*)d_in[0];
    const float* Wih   = (const float*)d_in[1];
    const float* Whh   = (const float*)d_in[2];
    const float* bih   = (const float*)d_in[3];
    const float* bhh   = (const float*)d_in[4];
    const float* Whead = (const float*)d_in[5];
    const float* bhead = (const float*)d_in[6];
    float* out = (float*)d_out;
    float* ws  = (float*)d_ws;

    const int B = in_sizes[0] / (T_STEPS * F_IN);
    const int blocks = (B + 127) / 128;

    hipLaunchKernelGGL(prep_kernel, dim3(1), dim3(256), 0, stream,
                       Wih, Whh, bih, bhh, Whead, ws);
    hipLaunchKernelGGL(lstm_kernel, dim3(blocks), dim3(256), 0, stream,
                       x, ws, bhead, out, B);
}